// Round 17
// baseline (2195.232 us; speedup 1.0000x reference)
//
#include <hip/hip_runtime.h>

// RecurrentEncoder: proj(16->512)+relu, 3-layer LSTM (H=512), out head (512->16).
// B=256, T=128. Round 17: r16 skeleton with acts loaded STRAIGHT TO VGPRS
// (plain cached global loads, 2x8-tile double-buffered named regs, compiler-
// scheduled waitcnts) — the DMA->LDS->VGPR round trip removed. LDS now carries
// only left-half W (64 KB) + tiny h-stage; LDS traffic/WG/step 768->256 KB.
// All else r15/r16-proven: 192 WGs (l,mg,n), XCD colocation + XCC_ID rendezvous,
// own-ring L2 / cross-ring L3 exchange, right-half W in VGPRs, left-first
// ordering, per-WG flags + __syncthreads publish, verified 32x32x16 MFMA.

typedef __attribute__((ext_vector_type(8)))  short bf16x8;
typedef __attribute__((ext_vector_type(16))) float f32x16;
typedef __attribute__((ext_vector_type(8)))  unsigned short us8;

#define B_  256
#define T_  128
#define FIN 16
#define H_  512
#define G4  2048
#define SLAB 131072   // shorts per (t,l) slab
#define MF(A,B,C) __builtin_amdgcn_mfma_f32_32x32x16_bf16(A,B,C,0,0,0)

static __device__ __forceinline__ float bf2f(unsigned short u){
  return __uint_as_float(((unsigned)u) << 16);
}
static __device__ __forceinline__ unsigned short f2bf(float f){  // RNE
  unsigned u = __float_as_uint(f);
  u += 0x7fffu + ((u >> 16) & 1u);
  return (unsigned short)(u >> 16);
}
static __device__ __forceinline__ float sigm(float x){ return 1.f/(1.f + __expf(-x)); }
static __device__ __forceinline__ float tanh_(float x){ return 1.f - 2.f/(__expf(2.f*x) + 1.f); }

// Wave-autonomous slot wait (r8-r16 proven): lane i polls slots[i&31].
static __device__ __forceinline__ void wave_wait(const int* slotbase, int v){
  int guard = 0;
  for (;;){
    int s = __hip_atomic_load((const int*)(slotbase + (threadIdx.x & 31)),
                              __ATOMIC_RELAXED, __HIP_MEMORY_SCOPE_AGENT);
    if (__all(s >= v) || guard++ > (1 << 17)) break;
    __builtin_amdgcn_s_sleep(2);
  }
  asm volatile("" ::: "memory");
}

// ================= prep kernels (verified) =================

// lstm_w fp32 [3][1024][2048] -> bf16, 32x32x16 A-frag order.
__global__ __launch_bounds__(256) void k_wconv(const float* __restrict__ w,
                                               unsigned short* __restrict__ wfo){
  long idx = (long)blockIdx.x*256 + threadIdx.x;   // 786432
  int lane = (int)(idx & 63);
  int s    = (int)((idx >> 6) & 63);
  int Jb   = (int)((idx >> 12) & 63);
  int l    = (int)(idx >> 18);
  int jp = Jb*32 + (lane & 31);
  int co = (jp & 3)*512 + (jp >> 2);
  int k0 = s*16 + (lane >> 5)*8;
  us8 o;
  #pragma unroll
  for (int e = 0; e < 8; ++e)
    o[e] = f2bf(w[((long)(l*1024 + k0 + e))*2048 + co]);
  *(us8*)(wfo + idx*8) = o;
}

// xp = relu(x @ pw + pb) -> bf16 in TILED layout (r12-verified).
__global__ __launch_bounds__(256) void k_xp(const float* __restrict__ x,
                                            const float* __restrict__ pw,
                                            const float* __restrict__ pb,
                                            unsigned short* __restrict__ xpt){
  __shared__ float sw[FIN*H_];
  __shared__ float sb[H_];
  int tid = threadIdx.x;
  for (int i = tid; i < FIN*H_; i += 256) sw[i] = pw[i];
  for (int i = tid; i < H_;     i += 256) sb[i] = pb[i];
  __syncthreads();
  int r0 = blockIdx.x * 64;
  int c0 = tid * 2;
  int s  = c0 >> 4, kl = c0 & 15;
  for (int rr = 0; rr < 64; ++rr){
    int r = r0 + rr;
    int b = r >> 7, t = r & 127;
    const float* xr = x + (long)r*FIN;
    float a0 = sb[c0], a1 = sb[c0+1];
    #pragma unroll
    for (int f = 0; f < FIN; ++f){
      float xv = xr[f];
      a0 += xv * sw[f*H_ + c0];
      a1 += xv * sw[f*H_ + c0 + 1];
    }
    ushort2 tmp;
    tmp.x = f2bf(fmaxf(a0, 0.f));
    tmp.y = f2bf(fmaxf(a1, 0.f));
    long off = (long)t*SLAB
             + ((((b>>7)*4 + ((b>>5)&3))*32 + s) << 9)
             + ((b&31) + ((kl>>3)<<5))*8 + (kl&7);
    *(ushort2*)(xpt + off) = tmp;
  }
}

// y = h2(tiled slab t,l=2) @ out_w + out_b ; grid 2048 (r12-verified)
__global__ __launch_bounds__(256) void k_out(const unsigned short* __restrict__ ring,
                                             const float* __restrict__ ow,
                                             const float* __restrict__ ob,
                                             float* __restrict__ dout){
  __shared__ float sw[H_*16];
  int tid = threadIdx.x;
  for (int i = tid; i < H_*16; i += 256) sw[i] = ow[i];
  __syncthreads();
  int r0 = blockIdx.x * 16;
  int rr = tid >> 4, o = tid & 15;
  int r = r0 + rr;
  int b = r >> 7, t = r & 127;
  long tb = ((long)t*3 + 2)*SLAB + (((b>>7)*4 + ((b>>5)&3)) << 14);
  float acc = ob[o];
  for (int k8 = 0; k8 < 64; ++k8){
    long off = tb + ((long)(k8 >> 1) << 9) + ((b&31) + ((k8&1)<<5))*8;
    us8 v = *(const us8*)(ring + off);
    #pragma unroll
    for (int e = 0; e < 8; ++e) acc += bf2f(v[e]) * sw[(k8*8 + e)*16 + o];
  }
  dout[(long)r*16 + o] = acc;
}

// ================= persistent RNN kernel =================

// Load one 8-tile group of acts into named registers (plain cached loads;
// compiler inserts/schedules the vmcnt waits and keeps 16 tiles in flight).
#define LDB8(V, G) { \
  V##0 = *(const bf16x8*)(gsrc + ((G)*8+0)*512); \
  V##1 = *(const bf16x8*)(gsrc + ((G)*8+1)*512); \
  V##2 = *(const bf16x8*)(gsrc + ((G)*8+2)*512); \
  V##3 = *(const bf16x8*)(gsrc + ((G)*8+3)*512); \
  V##4 = *(const bf16x8*)(gsrc + ((G)*8+4)*512); \
  V##5 = *(const bf16x8*)(gsrc + ((G)*8+5)*512); \
  V##6 = *(const bf16x8*)(gsrc + ((G)*8+6)*512); \
  V##7 = *(const bf16x8*)(gsrc + ((G)*8+7)*512); }

// Left-half k-step: W from LDS (J0 at byte 0, J1 at byte 32768), act in reg.
#define KL(V, I, RELU) { \
  bf16x8 w0 = *(const bf16x8*)(Wl + (((I)*64 + lane) << 4)); \
  bf16x8 w1 = *(const bf16x8*)(Wl + (32768 + (((I)*64 + lane) << 4))); \
  bf16x8 b = V; \
  if (RELU){ _Pragma("unroll") for (int e = 0; e < 8; ++e) if (b[e] < 0) b[e] = 0; } \
  a0 = MF(w0, b, a0); a1 = MF(w1, b, a1); }

// Right-half k-step: W from registers, act in reg — zero LDS.
#define KR(V, I) { a0 = MF(wr0[I], V, a0); a1 = MF(wr1[I], V, a1); }

#define KL8(V, G, R) { KL(V##0,(G)*8+0,R) KL(V##1,(G)*8+1,R) KL(V##2,(G)*8+2,R) \
  KL(V##3,(G)*8+3,R) KL(V##4,(G)*8+4,R) KL(V##5,(G)*8+5,R) \
  KL(V##6,(G)*8+6,R) KL(V##7,(G)*8+7,R) }
#define KR8(V, G) { KR(V##0,(G)*8+0) KR(V##1,(G)*8+1) KR(V##2,(G)*8+2) \
  KR(V##3,(G)*8+3) KR(V##4,(G)*8+4) KR(V##5,(G)*8+5) \
  KR(V##6,(G)*8+6) KR(V##7,(G)*8+7) }

// 32 tiles per half, 2x8 double-buffered named register groups.
#define GEMML(R) { LDB8(bA,0) LDB8(bB,1) KL8(bA,0,R) LDB8(bA,2) \
                   KL8(bB,1,R) LDB8(bB,3) KL8(bA,2,R) KL8(bB,3,R) }
#define GEMMR    { LDB8(bA,0) LDB8(bB,1) KR8(bA,0) LDB8(bA,2) \
                   KR8(bB,1) LDB8(bB,3) KR8(bA,2) KR8(bB,3) }

// hstage: [32 rows][stride 24 shorts].
#define CELL1(A, JB) { _Pragma("unroll") \
  for (int q = 0; q < 4; ++q){ \
    float iv = A[4*q+0], gv = A[4*q+1], fv = A[4*q+2], ov = A[4*q+3]; \
    float cp = cs##JB[q]; \
    float cn = sigm(fv + 1.f)*cp + sigm(iv)*tanh_(gv); \
    float hn = sigm(ov)*tanh_(cn); \
    cs##JB[q] = cn; \
    hst[l31*24 + JB*8 + 2*q + l5] = f2bf(hn); } }

// grid 256, active 192: g = bid&7 (<6), l = g>>1, mg = g&1, n = bid>>3.
// block 256 = 4 waves. LDS: W-left 64 KB + per-wave h-stage (163840 requested
// to keep 1 WG/CU -> all 192 co-resident, spin-safe).
__global__ __launch_bounds__(256, 1) void k_rnn(
    const unsigned short* __restrict__ wf, const float* __restrict__ lb,
    unsigned short* ownring, unsigned short* crossring,
    const unsigned short* __restrict__ xpt,
    int* stepslots, int* xcdslots, int sepAvail)
{
  extern __shared__ unsigned char Wl[];     // 163840
  const int bid = blockIdx.x;
  const int g = bid & 7;
  if (g >= 6) return;
  const int l = g >> 1, mg = g & 1;
  const int n = bid >> 3;
  const int tid = threadIdx.x;
  const int lane = tid & 63;
  const int wv = tid >> 6;
  const int l5 = lane >> 5, l31 = lane & 31;
  const int tilebase = (mg*4 + wv) << 5;                 // tile row for this wave
  unsigned short* hst = (unsigned short*)(Wl + 65536 + wv*4096);

  const unsigned short* wbase = wf + ((long)(l*64 + n*2))*4096*8;

  // ---- preload LEFT-half W into LDS: J0 s=0..31 -> bytes [0,32K),
  //      J1 s=0..31 -> bytes [32K,64K). Source J1 block at +32768 SHORTS. ----
  {
    us8* dst = (us8*)Wl;
    const us8* sj0 = (const us8*)wbase;
    const us8* sj1 = (const us8*)(wbase + 32768);
    for (int i = tid; i < 4096; i += 256)
      dst[i] = (i < 2048) ? sj0[i] : sj1[i - 2048];
  }
  // ---- preload RIGHT-half W (s=32..63, both J) into REGISTERS ----
  bf16x8 wr0[32], wr1[32];
  #pragma unroll
  for (int i = 0; i < 32; ++i){
    wr0[i] = *(const bf16x8*)(wbase + ((long)((32+i)*64 + lane))*8);
    wr1[i] = *(const bf16x8*)(wbase + 32768 + ((long)((32+i)*64 + lane))*8);
  }
  // ---- bias acc-init (D frag: j'_local = (r&3)+8*(r>>2)+4*l5; verified) ----
  f32x16 bias0, bias1;
  #pragma unroll
  for (int r = 0; r < 16; ++r){
    int hc0 = (n*2 + 0)*8 + 2*(r>>2) + l5;
    int hc1 = (n*2 + 1)*8 + 2*(r>>2) + l5;
    bias0[r] = lb[l*G4 + (r&3)*512 + hc0];
    bias1[r] = lb[l*G4 + (r&3)*512 + hc1];
  }
  float cs0[4] = {0.f,0.f,0.f,0.f}, cs1[4] = {0.f,0.f,0.f,0.f};
  __syncthreads();

  // ---- XCD rendezvous (r10-proven; G16-safe fallback) ----
  unsigned myxcd = 0;
  asm volatile("s_getreg_b32 %0, hwreg(HW_REG_XCC_ID)" : "=s"(myxcd));
  if (tid == 0)
    __hip_atomic_store(xcdslots + g*32 + n, 1 + (int)myxcd,
                       __ATOMIC_RELAXED, __HIP_MEMORY_SCOPE_AGENT);
  int uni;
  {
    int guard = 0, s = 0;
    for (;;){
      s = __hip_atomic_load((const int*)(xcdslots + g*32 + (lane & 31)),
                            __ATOMIC_RELAXED, __HIP_MEMORY_SCOPE_AGENT);
      if (__all(s >= 1) || guard++ > (1 << 17)) break;
      __builtin_amdgcn_s_sleep(2);
    }
    uni = __all(s == 1 + (int)myxcd);
    asm volatile("" ::: "memory");
  }
  const int ownSep = (sepAvail && uni) ? 1 : 0;
  const unsigned short* ownr = ownSep ? ownring : crossring;

  // ---- per-WG flags (r12-proven): [g][n] ----
  const int* sOwn  = stepslots + g*32;
  const int* sPrev = stepslots + (g - 2)*32;
  int* myFlag = stepslots + g*32 + n;

  bf16x8 bA0,bA1,bA2,bA3,bA4,bA5,bA6,bA7;
  bf16x8 bB0,bB1,bB2,bB3,bB4,bB5,bB6,bB7;

  for (int t = 0; t < T_; ++t){
    f32x16 a0 = bias0, a1 = bias1;

    // ---- LEFT half first (own-publish latency hides under this for l>0) ----
    if (l == 0){
      const unsigned short* gsrc = xpt + (long)t*SLAB + ((long)tilebase << 9)
                                 + lane*8;
      GEMML(0)
    } else {
      wave_wait(sPrev, t + 1);
      const unsigned short* gsrc = crossring + ((long)t*3 + (l-1))*SLAB
                                 + ((long)tilebase << 9) + lane*8;
      GEMML(1)     // cross stores raw h; consumer applies relu
    }
    // ---- RIGHT half: own h[t-1]; W in regs, acts in regs — zero LDS ----
    if (t > 0){
      wave_wait(sOwn, t);
      const unsigned short* gsrc = ownr + ((long)(t-1)*3 + l)*SLAB
                                 + ((long)tilebase << 9) + lane*8;
      GEMMR
    }

    // ---- LSTM cell (regs) -> per-wave LDS stage -> ONE coalesced 1 KB store ----
    CELL1(a0, 0)
    CELL1(a1, 1)
    asm volatile("s_waitcnt lgkmcnt(0)" ::: "memory");
    __builtin_amdgcn_sched_barrier(0);
    {
      us8 v = *(const us8*)(hst + l31*24 + l5*8);
      long off = ((long)t*3 + l)*SLAB + ((long)(tilebase + n) << 9) + lane*8;
      if (ownSep) *(us8*)(ownring + off) = v;         // cached -> XCD L2 (dirty)
      *(volatile us8*)(crossring + off) = v;           // write-through -> L3
    }
    __syncthreads();   // full drain (all 4 waves' stores + LDS) before publish
    if (tid == 0)
      __hip_atomic_store(myFlag, t + 1, __ATOMIC_RELAXED, __HIP_MEMORY_SCOPE_AGENT);
  }
}

// ================= round-0 fallback (compact) kernels =================

__global__ __launch_bounds__(256) void k_wconv0(const float* __restrict__ w,
                                                unsigned short* __restrict__ wf){
  long d8 = ((long)blockIdx.x*256 + threadIdx.x) * 8;
  int lane = (int)((d8 >> 3) & 63);
  int s    = (int)((d8 >> 9) & 31);
  int J    = (int)((d8 >> 14) & 127);
  int l    = (int)(d8 >> 21);
  int jj = lane & 15, khi = lane >> 4;
  int jp = J*16 + jj;
  int co = (jp & 3)*512 + (jp >> 2);
  int kbase = s*32 + khi*8;
  us8 o;
  #pragma unroll
  for (int e = 0; e < 8; ++e)
    o[e] = f2bf(w[((long)(l*1024 + kbase + e))*2048 + co]);
  *(us8*)(wf + d8) = o;
}

__global__ void k_iout(float* __restrict__ dout, const float* __restrict__ ob){
  int i = blockIdx.x*256 + threadIdx.x;
  if (i < B_*T_*16) dout[i] = ob[i & 15];
}

__global__ __launch_bounds__(256, 2) void k_stage0(
    const float* __restrict__ x, const float* __restrict__ pw, const float* __restrict__ pb,
    const unsigned short* __restrict__ wf, const float* __restrict__ lb,
    const float* __restrict__ ow, float* __restrict__ dout,
    float* __restrict__ cbuf, unsigned short* __restrict__ hb,
    int t, int l)
{
  __shared__ unsigned char Ab[32*2048];
  __shared__ float gsm[32*36];
  __shared__ float xrow[32*16];
  __shared__ float hcell[32*8];

  const int tid = threadIdx.x;
  const int bid = blockIdx.x;
  const int m = bid >> 6;
  const int n = ((bid & 7) << 3) | ((bid >> 3) & 7);
  const int pwr = t & 1, prd = pwr ^ 1;
  const int bg0 = m * 32;

  {
    const unsigned short* src = hb + (((long)prd*3 + l)*256 + bg0)*512;
    for (int i = 0; i < 8; ++i){
      int cid = tid + 256*i;
      int row = cid >> 6, cc = cid & 63;
      us8 v = *(const us8*)(src + (long)row*512 + cc*8);
      *(us8*)(Ab + ((row*2048 + 1024 + cc*16) ^ ((row & 7) << 4))) = v;
    }
  }
  if (l > 0){
    const unsigned short* src = hb + (((long)pwr*3 + (l-1))*256 + bg0)*512;
    for (int i = 0; i < 8; ++i){
      int cid = tid + 256*i;
      int row = cid >> 6, cc = cid & 63;
      us8 v = *(const us8*)(src + (long)row*512 + cc*8);
      #pragma unroll
      for (int e = 0; e < 8; ++e) v[e] = (v[e] & 0x8000u) ? (unsigned short)0 : v[e];
      *(us8*)(Ab + ((row*2048 + cc*16) ^ ((row & 7) << 4))) = v;
    }
  } else {
    {
      int e2 = tid*2;
      int br = e2 >> 4, f = e2 & 15;
      const float* xr = x + ((long)(bg0 + br)*T_ + t)*FIN;
      xrow[e2] = xr[f]; xrow[e2+1] = xr[f+1];
    }
    __syncthreads();
    for (int i = 0; i < 8; ++i){
      int cid = tid + 256*i;
      int row = cid >> 6, cc = cid & 63;
      int c0 = cc*8;
      us8 vv;
      #pragma unroll
      for (int j = 0; j < 8; ++j){
        float a = pb[c0 + j];
        #pragma unroll
        for (int f = 0; f < FIN; ++f) a += xrow[row*16 + f] * pw[f*H_ + c0 + j];
        vv[j] = f2bf(fmaxf(a, 0.f));
      }
      *(us8*)(Ab + ((row*2048 + cc*16) ^ ((row & 7) << 4))) = vv;
    }
  }
  __syncthreads();

  const int lane = tid & 63, wid = tid >> 6;
  const int wm = wid >> 1, wn = wid & 1;
  const int J = n*2 + wn;
  const int arow = wm*16 + (lane & 15);
  const unsigned abase = (unsigned)arow*2048 + ((lane >> 4) << 4);
  const unsigned axor = (unsigned)((arow & 7) << 4);
  const unsigned short* bp = wf + ((((long)l*128 + J)*32)*64 + lane)*8;

  typedef __attribute__((ext_vector_type(4))) float f32x4;
  f32x4 acc = {0.f, 0.f, 0.f, 0.f};
  #pragma unroll
  for (int s = 0; s < 32; ++s){
    bf16x8 af = *(const bf16x8*)(Ab + ((abase + s*64) ^ axor));
    bf16x8 bfr = *(const bf16x8*)(bp + (long)s*512);
    acc = __builtin_amdgcn_mfma_f32_16x16x32_bf16(af, bfr, acc, 0, 0, 0);
  }
  {
    int colb = wn*16 + (lane & 15);
    int rowb = wm*16 + ((lane >> 4) << 2);
    #pragma unroll
    for (int r = 0; r < 4; ++r) gsm[(rowb + r)*36 + colb] = acc[r];
  }
  __syncthreads();

  {
    int bl = tid >> 3, hc = tid & 7;
    float4 g4 = *(float4*)(&gsm[bl*36 + hc*4]);
    int hcol = n*8 + hc;
    int bgl = bg0 + bl;
    float iv = g4.x + lb[l*G4 + hcol];
    float gv = g4.y + lb[l*G4 + 512 + hcol];
    float fv = g4.z + lb[l*G4 + 1024 + hcol];
    float ov = g4.w + lb[l*G4 + 1536 + hcol];
    long coff = ((long)l*256 + bgl)*512 + hcol;
    float cp = cbuf[coff];
    float cn = sigm(fv + 1.f)*cp + sigm(iv)*tanh_(gv);
    float hn = sigm(ov)*tanh_(cn);
    cbuf[coff] = cn;
    hb[(((long)pwr*3 + l)*256 + bgl)*512 + hcol] = f2bf(hn);
    if (l == 2) hcell[bl*8 + hc] = hn;
  }
  if (l == 2){
    __syncthreads();
    #pragma unroll
    for (int q = 0; q < 2; ++q){
      int oid = tid + 256*q;
      int bl = oid >> 4, o = oid & 15;
      float a = 0.f;
      #pragma unroll
      for (int hc = 0; hc < 8; ++hc) a += hcell[bl*8 + hc] * ow[(n*8 + hc)*16 + o];
      atomicAdd(dout + ((long)(bg0 + bl)*T_ + t)*16 + o, a);
    }
  }
}

// ================= launch =================

extern "C" void kernel_launch(void* const* d_in, const int* in_sizes, int n_in,
                              void* d_out, int out_size, void* d_ws, size_t ws_size,
                              hipStream_t stream)
{
  const float* x  = (const float*)d_in[0];
  const float* pw = (const float*)d_in[1];
  const float* pb = (const float*)d_in[2];
  const float* lw = (const float*)d_in[3];
  const float* lb = (const float*)d_in[4];
  const float* ow = (const float*)d_in[5];
  const float* ob = (const float*)d_in[6];
  float* dout = (float*)d_out;

  const size_t RING = 128ull*3*SLAB*2;                 // 100.66 MB
  char* ws = (char*)d_ws;
  size_t off = 0;
  auto carve = [&](size_t bytes){ char* p = ws + off; off += (bytes + 255) & ~(size_t)255; return p; };

  unsigned short* wf    = (unsigned short*)carve(3ull*64*4096*8*2);   // 12.58 MB
  unsigned short* cross = (unsigned short*)carve(RING);               // 100.66 MB
  unsigned short* xpt   = (unsigned short*)carve(128ull*SLAB*2);      // 33.55 MB
  int*            steps = (int*)carve(1024);                          // [6][32]
  int*            xcds  = (int*)carve(1024);
  size_t need_mid = off;                                              // ~146.9 MB
  unsigned short* own   = (unsigned short*)carve(RING);               // +100.66 MB
  size_t need_lux = off;                                              // ~247.5 MB

  int mode = (ws_size >= need_lux) ? 2 : (ws_size >= need_mid ? 1 : 0);
  if (mode){
    if (hipFuncSetAttribute((const void*)k_rnn,
                            hipFuncAttributeMaxDynamicSharedMemorySize,
                            163840) != hipSuccess)
      mode = 0;
  }

  if (mode){
    int sepAvail = (mode == 2) ? 1 : 0;
    unsigned short* ownp = sepAvail ? own : cross;
    hipMemsetAsync(steps, 0, 2048, stream);            // steps + xcds adjacent
    k_wconv<<<3072, 256, 0, stream>>>(lw, wf);
    k_xp<<<512, 256, 0, stream>>>(x, pw, pb, xpt);
    k_rnn<<<256, 256, 163840, stream>>>(wf, lb, ownp, cross, xpt,
                                        steps, xcds, sepAvail);
    k_out<<<2048, 256, 0, stream>>>(cross, ow, ob, dout);
  } else {
    // round-0 compact fallback (proven, 2199 us)
    size_t o2 = 0;
    auto carve2 = [&](size_t bytes){ char* p = ws + o2; o2 += (bytes + 255) & ~(size_t)255; return p; };
    unsigned short* wf0   = (unsigned short*)carve2(3ull*1024*2048*2);
    float*          cbuf0 = (float*)carve2(3ull*256*512*4);
    unsigned short* hbuf0 = (unsigned short*)carve2(2ull*3*256*512*2);
    hipMemsetAsync(cbuf0, 0, 3ull*256*512*4 + 2ull*3*256*512*2, stream);
    k_wconv0<<<3072, 256, 0, stream>>>(lw, wf0);
    k_iout<<<2048, 256, 0, stream>>>(dout, ob);
    for (int t = 0; t < T_; ++t)
      for (int l = 0; l < 3; ++l)
        k_stage0<<<512, 256, 0, stream>>>(x, pw, pb, wf0, lb, ow, dout,
                                          cbuf0, hbuf0, t, l);
  }
}